// Round 13
// baseline (337.984 us; speedup 1.0000x reference)
//
#include <hip/hip_runtime.h>
#include <hip/hip_bf16.h>
#include <cstdint>
#include <cstddef>

#define S 2048
#define D 4096
#define H 32
#define G 8
#define DH 128
#define HD (H*DH)   // 4096
#define GD (G*DH)   // 1024

typedef __bf16 bf16;
typedef __bf16 bf16x4 __attribute__((ext_vector_type(4)));
typedef __bf16 bf16x8 __attribute__((ext_vector_type(8)));
typedef float f32x4 __attribute__((ext_vector_type(4)));

__device__ __forceinline__ void gload16(const void* g, void* l) {
    __builtin_amdgcn_global_load_lds(
        (const __attribute__((address_space(1))) void*)g,
        (__attribute__((address_space(3))) void*)l, 16, 0, 0);
}

#define FENCE() asm volatile("" ::: "memory")
#define BARRIER() do { FENCE(); __builtin_amdgcn_s_barrier(); FENCE(); } while (0)
#define VMCNT(n)  asm volatile("s_waitcnt vmcnt(" #n ")" ::: "memory")
#define LGKM0()   do { asm volatile("s_waitcnt lgkmcnt(0)" ::: "memory"); \
                       __builtin_amdgcn_sched_barrier(0); } while (0)

// ---------------------------------------------------------------- fused prep:
// [0,512): cast x ; [512,1536): Wq^T ; [1536,1792): Wk^T ; [1792,2048): Wv^T
// (Wo^T is hidden under flash_fwd6's spare bandwidth - blocks [512,576) there.)
__global__ __launch_bounds__(256) void prep_fused(
    const float* __restrict__ x, bf16* __restrict__ xb,
    const float* __restrict__ Wq, const float* __restrict__ Wk,
    const float* __restrict__ Wv, bf16* __restrict__ Wqkvt)
{
    const int b = blockIdx.x, tid = threadIdx.x;
    if (b < 512) {
        int i = b * 4096 + tid;
        #pragma unroll
        for (int it = 0; it < 16; ++it, i += 256) {
            float4 v = reinterpret_cast<const float4*>(x)[i];
            bf16x4 o = { (bf16)v.x, (bf16)v.y, (bf16)v.z, (bf16)v.w };
            reinterpret_cast<bf16x4*>(xb)[i] = o;
        }
        return;
    }
    const float* in; bf16* out; int Cc, bx, by;
    if (b < 1536)      { int tb = b - 512;  in = Wq; out = Wqkvt;                       Cc = HD; bx = tb & 15; by = tb >> 4; }
    else if (b < 1792) { int tb = b - 1536; in = Wk; out = Wqkvt + (size_t)HD * D;      Cc = GD; bx = tb & 3;  by = tb >> 2; }
    else               { int tb = b - 1792; in = Wv; out = Wqkvt + (size_t)(HD+GD) * D; Cc = GD; bx = tb & 3;  by = tb >> 2; }
    const int r0 = by * 64 + (tid & 7) * 8;
    const int c0 = bx * 256 + (tid >> 3) * 8;
    bf16 m[8][8];
    #pragma unroll
    for (int j = 0; j < 8; ++j) {
        const float* p = in + (size_t)(r0 + j) * Cc + c0;
        float4 a = *reinterpret_cast<const float4*>(p);
        float4 bq = *reinterpret_cast<const float4*>(p + 4);
        m[j][0] = (bf16)a.x;  m[j][1] = (bf16)a.y;  m[j][2] = (bf16)a.z;  m[j][3] = (bf16)a.w;
        m[j][4] = (bf16)bq.x; m[j][5] = (bf16)bq.y; m[j][6] = (bf16)bq.z; m[j][7] = (bf16)bq.w;
    }
    #pragma unroll
    for (int i = 0; i < 8; ++i) {
        bf16x8 ov;
        #pragma unroll
        for (int j = 0; j < 8; ++j) ov[j] = m[j][i];
        *reinterpret_cast<bf16x8*>(out + (size_t)(c0 + i) * D + r0) = ov;
    }
}

// ---------------------------------------------------------------- fused rope + V^T
__global__ __launch_bounds__(256) void rope_vt_fused(
    bf16* __restrict__ Qb, bf16* __restrict__ Kb,
    const bf16* __restrict__ Vb, bf16* __restrict__ VtG,
    const float* __restrict__ cosT, const float* __restrict__ sinT, float qs)
{
    const int b = blockIdx.x, tid = threadIdx.x;
    if (b < 20480) {
        bf16* Y; int ncols, idx; float scale;
        if (b < 16384) { Y = Qb; ncols = HD; idx = b * 256 + tid;           scale = qs; }
        else           { Y = Kb; ncols = GD; idx = (b - 16384) * 256 + tid; scale = 1.0f; }
        int pairs = ncols >> 1;
        int s = idx / pairs;
        int p = idx - s * pairs;
        int head = p >> 6;
        int d = p & 63;
        size_t base = (size_t)s * ncols + head * DH;
        float c  = cosT[s * DH + d];
        float sn = sinT[s * DH + d];
        float a = (float)Y[base + d];
        float bb = (float)Y[base + d + 64];
        Y[base + d]      = (bf16)((a * c - bb * sn) * scale);
        Y[base + d + 64] = (bf16)((bb * c + a * sn) * scale);
        return;
    }
    const int tb = b - 20480;
    const int r0 = (tb >> 2) * 64 + (tid & 7) * 8;
    const int c0 = (tb & 3) * 256 + (tid >> 3) * 8;
    bf16 m[8][8];
    #pragma unroll
    for (int j = 0; j < 8; ++j) {
        bf16x8 v = *reinterpret_cast<const bf16x8*>(Vb + (size_t)(r0 + j) * GD + c0);
        #pragma unroll
        for (int i = 0; i < 8; ++i) m[j][i] = v[i];
    }
    #pragma unroll
    for (int i = 0; i < 8; ++i) {
        bf16x8 ov;
        #pragma unroll
        for (int j = 0; j < 8; ++j) ov[j] = m[j][i];
        *reinterpret_cast<bf16x8*>(VtG + (size_t)(c0 + i) * S + r0) = ov;
    }
}

// ---------------------------------------------------------------- standalone kernels (fallback path)
__global__ __launch_bounds__(256) void cast_f32_bf16(const float* __restrict__ in,
                                                     bf16* __restrict__ out, int n4)
{
    int i = blockIdx.x * 256 + threadIdx.x;
    if (i < n4) {
        float4 v = reinterpret_cast<const float4*>(in)[i];
        bf16x4 o = { (bf16)v.x, (bf16)v.y, (bf16)v.z, (bf16)v.w };
        reinterpret_cast<bf16x4*>(out)[i] = o;
    }
}

template<bool IN_F32>
__global__ __launch_bounds__(256) void transpose_to_bf16(
    const void* __restrict__ in, bf16* __restrict__ out, int R, int C)
{
    const int r0 = blockIdx.y * 64 + (threadIdx.x & 7) * 8;
    const int c0 = blockIdx.x * 256 + (threadIdx.x >> 3) * 8;
    bf16 m[8][8];
    #pragma unroll
    for (int j = 0; j < 8; ++j) {
        if constexpr (IN_F32) {
            const float* p = (const float*)in + (size_t)(r0 + j) * C + c0;
            float4 a = *reinterpret_cast<const float4*>(p);
            float4 b = *reinterpret_cast<const float4*>(p + 4);
            m[j][0] = (bf16)a.x; m[j][1] = (bf16)a.y; m[j][2] = (bf16)a.z; m[j][3] = (bf16)a.w;
            m[j][4] = (bf16)b.x; m[j][5] = (bf16)b.y; m[j][6] = (bf16)b.z; m[j][7] = (bf16)b.w;
        } else {
            const bf16* p = (const bf16*)in + (size_t)(r0 + j) * C + c0;
            bf16x8 v = *reinterpret_cast<const bf16x8*>(p);
            #pragma unroll
            for (int i = 0; i < 8; ++i) m[j][i] = v[i];
        }
    }
    #pragma unroll
    for (int i = 0; i < 8; ++i) {
        bf16x8 ov;
        #pragma unroll
        for (int j = 0; j < 8; ++j) ov[j] = m[j][i];
        *reinterpret_cast<bf16x8*>(out + (size_t)(c0 + i) * R + r0) = ov;
    }
}

__global__ __launch_bounds__(256) void rope_inplace(bf16* __restrict__ Y,
                                                    const float* __restrict__ cosT,
                                                    const float* __restrict__ sinT,
                                                    int ncols, int total, float scale)
{
    int idx = blockIdx.x * 256 + threadIdx.x;
    if (idx >= total) return;
    int pairs = ncols >> 1;
    int s = idx / pairs;
    int p = idx - s * pairs;
    int head = p >> 6;
    int d = p & 63;
    size_t base = (size_t)s * ncols + head * DH;
    float c  = cosT[s * DH + d];
    float sn = sinT[s * DH + d];
    float a = (float)Y[base + d];
    float b = (float)Y[base + d + 64];
    Y[base + d]      = (bf16)((a * c - b * sn) * scale);
    Y[base + d + 64] = (bf16)((b * c + a * sn) * scale);
}

// ================================================================ QKV GEMM: 256x192, 256 blocks, r4 schedule
__global__ __launch_bounds__(512) void gemm192q(
    const bf16* __restrict__ A, const bf16* __restrict__ Bt,
    bf16* __restrict__ Qout, bf16* __restrict__ Kout, bf16* __restrict__ Vout, int K)
{
    extern __shared__ char smem[];   // buf d @ d*57344: A 32KB | B @ +32768 (24KB)
    const int tid = threadIdx.x, lane = tid & 63, wave = tid >> 6;
    const int wr = wave >> 2, wc = wave & 3;
    const int l15 = lane & 15, lhi = lane >> 4;
    const int r8 = lane >> 3, c8 = lane & 7;
    const int csw = ((c8 ^ r8) << 3);

    const int x = blockIdx.x & 7, bi = blockIdx.x >> 3;
    const int brow = (x >> 2) * 4 + (bi & 3);       // [0,8)
    const int bcol = (x & 3) * 8 + (bi >> 2);       // [0,32)
    const int bm = brow * 256, bn = bcol * 192;
    const int NT = K >> 6;

    auto stA = [&](int buf, int h, int L, int t) {
        int row0 = L * 128 + h * 64 + wave * 8;
        gload16(A + (size_t)(bm + row0 + r8) * K + (t << 6) + csw,
                smem + buf * 57344 + row0 * 128);
    };
    auto stB = [&](int buf, int u, int t) {
        int row0 = u * 64 + wave * 8;
        gload16(Bt + (size_t)(bn + row0 + r8) * K + (t << 6) + csw,
                smem + buf * 57344 + 32768 + row0 * 128);
    };
    auto rdA = [&](const char* Cb, int mh, int ks, bf16x8* af) {
        #pragma unroll
        for (int m = 0; m < 4; ++m) {
            int row = wr * 128 + mh * 64 + m * 16 + l15;
            int ch = (ks * 4 + lhi) ^ (l15 & 7);
            af[m] = *reinterpret_cast<const bf16x8*>(Cb + row * 128 + ch * 16);
        }
    };
    auto rdB = [&](const char* Cb, int ks, bf16x8* bfv) {
        #pragma unroll
        for (int n = 0; n < 3; ++n) {
            int row = wc * 48 + n * 16 + l15;
            int ch = (ks * 4 + lhi) ^ (l15 & 7);
            bfv[n] = *reinterpret_cast<const bf16x8*>(Cb + 32768 + row * 128 + ch * 16);
        }
    };

    f32x4 acc[8][3] = {};
    auto mm = [&](int mh, const bf16x8* af, const bf16x8* bfv) {
        LGKM0();
        __builtin_amdgcn_s_setprio(1);
        #pragma unroll
        for (int m = 0; m < 4; ++m)
            #pragma unroll
            for (int n = 0; n < 3; ++n)
                acc[mh * 4 + m][n] = __builtin_amdgcn_mfma_f32_16x16x32_bf16(
                    af[m], bfv[n], acc[mh * 4 + m][n], 0, 0, 0);
        __builtin_amdgcn_s_setprio(0);
    };

    stB(0, 0, 0); stB(0, 1, 0); stB(0, 2, 0);
    stA(0, 0, 0, 0); stA(0, 0, 1, 0);
    stA(0, 1, 0, 0); stA(0, 1, 1, 0);
    VMCNT(2);
    BARRIER();

    for (int t = 0; t < NT; ++t) {
        const char* cur = smem + (t & 1) * 57344;
        const int nb = (t + 1) & 1;
        const int tn = (t + 1 < NT) ? t + 1 : t;
        bf16x8 af[4], bk0[3], bk1[3];

        // ph1: (mh0, ks0)
        rdA(cur, 0, 0, af); rdB(cur, 0, bk0);
        stB(nb, 0, tn); stB(nb, 1, tn);
        mm(0, af, bk0);
        BARRIER();

        // ph2: (mh0, ks1)
        rdA(cur, 0, 1, af); rdB(cur, 1, bk1);
        stB(nb, 2, tn); stA(nb, 0, 0, tn);
        mm(0, af, bk1);
        VMCNT(4);
        BARRIER();

        // ph3: (mh1, ks0)
        rdA(cur, 1, 0, af);
        stA(nb, 0, 1, tn); stA(nb, 1, 0, tn);
        mm(1, af, bk0);
        BARRIER();

        // ph4: (mh1, ks1)
        rdA(cur, 1, 1, af);
        stA(nb, 1, 1, tn);
        mm(1, af, bk1);
        VMCNT(2);
        BARRIER();
    }

    #pragma unroll
    for (int mm_i = 0; mm_i < 8; ++mm_i) {
        int r0 = bm + wr * 128 + (mm_i >> 2) * 64 + (mm_i & 3) * 16 + lhi * 4;
        #pragma unroll
        for (int n = 0; n < 3; ++n) {
            int c = bn + wc * 48 + n * 16 + l15;
            #pragma unroll
            for (int j = 0; j < 4; ++j) {
                bf16 v = (bf16)acc[mm_i][n][j];
                if (c < HD)            Qout[(size_t)(r0 + j) * HD + c] = v;
                else if (c < HD + GD)  Kout[(size_t)(r0 + j) * GD + (c - HD)] = v;
                else                   Vout[(size_t)(r0 + j) * GD + (c - HD - GD)] = v;
            }
        }
    }
}

// ================================================================ Wo GEMM: 256x128, 3-buf, 2D XCD regions
__global__ __launch_bounds__(512, 2) void gemm3b(
    const bf16* __restrict__ A, const bf16* __restrict__ Bt,
    float* __restrict__ C, int N, int K)
{
    extern __shared__ char smem[];   // buf b @ b*49152: A 32KB, B @ +32768 (16KB)
    const int tid = threadIdx.x, lane = tid & 63, wave = tid >> 6;
    const int wr = wave >> 1, wc = wave & 1;
    const int l15 = lane & 15, lhi = lane >> 4;
    const int r8 = lane >> 3, c8 = lane & 7;
    const int csw = ((c8 ^ r8) << 3);

    const int x = blockIdx.x & 7, i = blockIdx.x >> 3;
    const int brow = (x >> 2) * 4 + (i & 3);
    const int bcol = (x & 3) * 8 + (i >> 2);
    const int bm = brow * 256, bn = bcol * 128;
    const int NT = K >> 6;

    auto stageA = [&](int buf, int L, int t) {
        int row0 = L * 64 + wave * 8;
        gload16(A + (size_t)(bm + row0 + r8) * K + (t << 6) + csw,
                smem + buf * 49152 + row0 * 128);
    };
    auto stageB = [&](int buf, int L, int t) {
        int row0 = L * 64 + wave * 8;
        gload16(Bt + (size_t)(bn + row0 + r8) * K + (t << 6) + csw,
                smem + buf * 49152 + 32768 + row0 * 128);
    };
    auto rdA = [&](const char* Ab, int ks, bf16x8* af) {
        #pragma unroll
        for (int m = 0; m < 4; ++m) {
            int row = wr * 64 + m * 16 + l15;
            int ch = (ks * 4 + lhi) ^ (l15 & 7);
            af[m] = *reinterpret_cast<const bf16x8*>(Ab + row * 128 + ch * 16);
        }
    };
    auto rdB = [&](const char* Bb, int ks, bf16x8* bfv) {
        #pragma unroll
        for (int n = 0; n < 4; ++n) {
            int row = wc * 64 + n * 16 + l15;
            int ch = (ks * 4 + lhi) ^ (l15 & 7);
            bfv[n] = *reinterpret_cast<const bf16x8*>(Bb + row * 128 + ch * 16);
        }
    };

    f32x4 acc[4][4] = {};

    #pragma unroll
    for (int L = 0; L < 4; ++L) stageA(0, L, 0);
    stageB(0, 0, 0); stageB(0, 1, 0);
    #pragma unroll
    for (int L = 0; L < 4; ++L) stageA(1, L, (1 < NT) ? 1 : 0);
    stageB(1, 0, (1 < NT) ? 1 : 0); stageB(1, 1, (1 < NT) ? 1 : 0);
    VMCNT(6);
    BARRIER();

    for (int t = 0; t < NT; ++t) {
        const char* Ab = smem + (t % 3) * 49152;
        const char* Bb = Ab + 32768;
        const int b2 = (t + 2) % 3;
        const int st = (t + 2 < NT) ? t + 2 : NT - 1;
        bf16x8 af[4], bk[4];

        rdB(Bb, 0, bk); rdA(Ab, 0, af);
        stageA(b2, 0, st); stageA(b2, 1, st);
        LGKM0();
        __builtin_amdgcn_s_setprio(1);
        #pragma unroll
        for (int m = 0; m < 4; ++m)
            #pragma unroll
            for (int n = 0; n < 4; ++n)
                acc[m][n] = __builtin_amdgcn_mfma_f32_16x16x32_bf16(af[m], bk[n], acc[m][n], 0, 0, 0);
        __builtin_amdgcn_s_setprio(0);

        rdB(Bb, 1, bk); rdA(Ab, 1, af);
        stageA(b2, 2, st); stageA(b2, 3, st);
        stageB(b2, 0, st); stageB(b2, 1, st);
        LGKM0();
        __builtin_amdgcn_s_setprio(1);
        #pragma unroll
        for (int m = 0; m < 4; ++m)
            #pragma unroll
            for (int n = 0; n < 4; ++n)
                acc[m][n] = __builtin_amdgcn_mfma_f32_16x16x32_bf16(af[m], bk[n], acc[m][n], 0, 0, 0);
        __builtin_amdgcn_s_setprio(0);

        VMCNT(6);
        BARRIER();
    }

    #pragma unroll
    for (int m = 0; m < 4; ++m) {
        int r0 = bm + wr * 64 + m * 16 + lhi * 4;
        #pragma unroll
        for (int n = 0; n < 4; ++n) {
            int c = bn + wc * 64 + n * 16 + l15;
            #pragma unroll
            for (int j = 0; j < 4; ++j)
                C[(size_t)(r0 + j) * N + c] = acc[m][n][j];
        }
    }
}

// ---------------------------------------------------------------- fallback GEMM (round-1)
#define BM 128
#define BN 128
#define BK 32
#define LDSK 40

template<bool OUT_BF16>
__global__ __launch_bounds__(256) void gemm_aBf16(
    const bf16* __restrict__ A,
    const float* __restrict__ B0, const float* __restrict__ B1,
    void* __restrict__ C0, void* __restrict__ C1,
    int M, int N, int K)
{
    __shared__ alignas(16) bf16 Al[BM][LDSK];
    __shared__ alignas(16) bf16 Bt[BN][LDSK];

    const float* __restrict__ B = blockIdx.z ? B1 : B0;
    void* __restrict__ C = blockIdx.z ? C1 : C0;

    const int tid  = threadIdx.x;
    const int lane = tid & 63;
    const int wave = tid >> 6;
    const int wm = (wave >> 1) * 64;
    const int wn = (wave & 1) * 64;
    const int bm = blockIdx.y * BM;
    const int bn = blockIdx.x * BN;
    const int l15 = lane & 15;
    const int lhi = lane >> 4;

    f32x4 acc[4][4] = {};

    for (int k0 = 0; k0 < K; k0 += BK) {
        #pragma unroll
        for (int it = 0; it < 2; ++it) {
            int idx = it * 256 + tid;
            int row = idx >> 2;
            int ko  = idx & 3;
            bf16x8 v = *reinterpret_cast<const bf16x8*>(
                A + (size_t)(bm + row) * K + k0 + ko * 8);
            *reinterpret_cast<bf16x8*>(&Al[row][ko * 8]) = v;
        }
        {
            int n = tid & 127;
            int kbase = (tid >> 7) * 8;
            const float* bp = B + (size_t)k0 * N + bn + n;
            #pragma unroll
            for (int half = 0; half < 2; ++half) {
                bf16x8 v;
                #pragma unroll
                for (int j = 0; j < 8; ++j)
                    v[j] = (bf16)bp[(size_t)(half * 16 + kbase + j) * N];
                *reinterpret_cast<bf16x8*>(&Bt[n][half * 16 + kbase]) = v;
            }
        }
        __syncthreads();

        bf16x8 af[4], bfv[4];
        #pragma unroll
        for (int m = 0; m < 4; ++m)
            af[m] = *reinterpret_cast<const bf16x8*>(&Al[wm + m * 16 + l15][lhi * 8]);
        #pragma unroll
        for (int n = 0; n < 4; ++n)
            bfv[n] = *reinterpret_cast<const bf16x8*>(&Bt[wn + n * 16 + l15][lhi * 8]);
        #pragma unroll
        for (int m = 0; m < 4; ++m)
            #pragma unroll
            for (int n = 0; n < 4; ++n)
                acc[m][n] = __builtin_amdgcn_mfma_f32_16x16x32_bf16(
                    af[m], bfv[n], acc[m][n], 0, 0, 0);
        __syncthreads();
    }

    #pragma unroll
    for (int m = 0; m < 4; ++m) {
        int r0 = bm + wm + m * 16 + lhi * 4;
        #pragma unroll
        for (int n = 0; n < 4; ++n) {
            int c = bn + wn + n * 16 + l15;
            #pragma unroll
            for (int j = 0; j < 4; ++j) {
                if constexpr (OUT_BF16)
                    reinterpret_cast<bf16*>(C)[(size_t)(r0 + j) * N + c] = (bf16)acc[m][n][j];
                else
                    reinterpret_cast<float*>(C)[(size_t)(r0 + j) * N + c] = acc[m][n][j];
            }
        }
    }
}

// ---------------------------------------------------------------- flash attention v6 + hidden Wo transpose
// Blocks [0,512): flash (unchanged r11 inner loop).
// Blocks [512,576): Wo [4096][4096] f32 -> Wot bf16 transpose riding flash's
// idle HBM bandwidth (flash runs at ~2.4% BW). Stream order guarantees Wot
// is complete before gemm3b launches.
#define QBLK 128
#define KVBLK 64
#define NQT (S/QBLK)
#define FLASH_BLOCKS (NQT*H)

template<bool MASK>
__device__ __forceinline__ void attn_tile(
    int t0, int q0w, int l15, int lhi,
    const bf16x8* qf, const char* Kl, const char* Vl, char* Plw,
    f32x4* o, float& m_i, float& l_i)
{
    f32x4 sc[4] = {};
    __builtin_amdgcn_s_setprio(1);
    #pragma unroll
    for (int n = 0; n < 4; ++n) {
        int row = n * 16 + l15;
        #pragma unroll
        for (int kk = 0; kk < 4; ++kk) {
            bf16x8 kf = *reinterpret_cast<const bf16x8*>(
                Kl + row * 256 + ((((kk * 4 + lhi)) ^ (l15 & 7)) << 4));
            sc[n] = __builtin_amdgcn_mfma_f32_16x16x32_bf16(kf, qf[kk], sc[n], 0, 0, 0);
        }
    }
    __builtin_amdgcn_s_setprio(0);

    const int qr = q0w + l15;
    float vals[16];
    #pragma unroll
    for (int n = 0; n < 4; ++n)
        #pragma unroll
        for (int j = 0; j < 4; ++j) {
            float v = sc[n][j];
            if constexpr (MASK) {
                int t = t0 + n * 16 + lhi * 4 + j;
                if (t > qr) v = -1e30f;
            }
            vals[n * 4 + j] = v;
        }

    float m8[8], m4[4];
    #pragma unroll
    for (int k = 0; k < 8; ++k) m8[k] = fmaxf(vals[k], vals[k + 8]);
    #pragma unroll
    for (int k = 0; k < 4; ++k) m4[k] = fmaxf(m8[k], m8[k + 4]);
    float mx = fmaxf(fmaxf(m4[0], m4[1]), fmaxf(m4[2], m4[3]));
    mx = fmaxf(mx, __shfl_xor(mx, 16));
    mx = fmaxf(mx, __shfl_xor(mx, 32));

    const float mnew = (mx <= m_i + 8.0f) ? m_i : mx;
    const float cr = exp2f(m_i - mnew);

    float p[16];
    #pragma unroll
    for (int k = 0; k < 16; ++k) p[k] = exp2f(vals[k] - mnew);
    float s8[8], s4[4];
    #pragma unroll
    for (int k = 0; k < 8; ++k) s8[k] = p[k] + p[k + 8];
    #pragma unroll
    for (int k = 0; k < 4; ++k) s4[k] = s8[k] + s8[k + 4];
    float rsum = (s4[0] + s4[1]) + (s4[2] + s4[3]);
    rsum += __shfl_xor(rsum, 16);
    rsum += __shfl_xor(rsum, 32);
    l_i = l_i * cr + rsum;
    m_i = mnew;

    #pragma unroll
    for (int n = 0; n < 4; ++n) {
        bf16x4 w = { (bf16)p[n*4+0], (bf16)p[n*4+1], (bf16)p[n*4+2], (bf16)p[n*4+3] };
        int off = (l15 << 7) + (((n << 5) + (lhi << 3)) ^ ((l15 & 7) << 4));
        *reinterpret_cast<bf16x4*>(Plw + off) = w;
    }

    float corr[4];
    #pragma unroll
    for (int j = 0; j < 4; ++j) corr[j] = __shfl(cr, lhi * 4 + j, 16);
    if ((corr[0] != 1.f) | (corr[1] != 1.f) | (corr[2] != 1.f) | (corr[3] != 1.f)) {
        #pragma unroll
        for (int n = 0; n < 8; ++n)
            #pragma unroll
            for (int j = 0; j < 4; ++j)
                o[n][j] *= corr[j];
    }

    __builtin_amdgcn_s_setprio(1);
    #pragma unroll
    for (int kk = 0; kk < 2; ++kk) {
        bf16x8 pf = *reinterpret_cast<const bf16x8*>(
            Plw + (l15 << 7) + ((((kk * 4 + lhi)) ^ (l15 & 7)) << 4));
        #pragma unroll
        for (int n = 0; n < 8; ++n) {
            int d = n * 16 + l15;
            bf16x8 vf = *reinterpret_cast<const bf16x8*>(
                Vl + (d << 7) + ((((kk * 4 + lhi)) ^ (d & 7)) << 4));
            o[n] = __builtin_amdgcn_mfma_f32_16x16x32_bf16(pf, vf, o[n], 0, 0, 0);
        }
    }
    __builtin_amdgcn_s_setprio(0);
}

__global__ __launch_bounds__(512) void flash_fwd6(
    const bf16* __restrict__ Q, const bf16* __restrict__ Kr,
    const bf16* __restrict__ VtG, bf16* __restrict__ ctx,
    const float* __restrict__ WoIn, bf16* __restrict__ WotOut)
{
    extern __shared__ char fsm[];   // buf b: K @ b*32768, V @ +16384; P @ 65536 (8x2KB)

    const int tid  = threadIdx.x;
    const int bid = blockIdx.x;

    if (bid >= FLASH_BLOCKS) {
        // ---- hidden Wo transpose: 64 blocks x 512 threads, 8 col-passes
        const int tb = bid - FLASH_BLOCKS;               // 0..63
        const int r0 = tb * 64 + (tid & 7) * 8;          // rows of Wo (HD dim)
        #pragma unroll 1
        for (int pass = 0; pass < 8; ++pass) {
            const int c0 = pass * 512 + (tid >> 3) * 8;  // cols of Wo (D dim)
            bf16 m[8][8];
            #pragma unroll
            for (int j = 0; j < 8; ++j) {
                const float* p = WoIn + (size_t)(r0 + j) * D + c0;
                float4 a = *reinterpret_cast<const float4*>(p);
                float4 b = *reinterpret_cast<const float4*>(p + 4);
                m[j][0] = (bf16)a.x; m[j][1] = (bf16)a.y; m[j][2] = (bf16)a.z; m[j][3] = (bf16)a.w;
                m[j][4] = (bf16)b.x; m[j][5] = (bf16)b.y; m[j][6] = (bf16)b.z; m[j][7] = (bf16)b.w;
            }
            #pragma unroll
            for (int i = 0; i < 8; ++i) {
                bf16x8 ov;
                #pragma unroll
                for (int j = 0; j < 8; ++j) ov[j] = m[j][i];
                *reinterpret_cast<bf16x8*>(WotOut + (size_t)(c0 + i) * HD + r0) = ov;
            }
        }
        return;
    }

    const int lane = tid & 63;
    const int wave = tid >> 6;
    const int l15 = lane & 15;
    const int lhi = lane >> 4;
    const int qt = (NQT - 1) - (bid >> 5);
    const int h  = ((bid & 7) << 2) | ((bid >> 3) & 3);
    const int g  = h >> 2;
    const int q0 = qt * QBLK;
    const int q0w = q0 + wave * 16;
    char* Plw = fsm + 65536 + wave * 2048;

    bf16x8 qf[4];
    {
        const bf16* qp = Q + (size_t)(q0w + l15) * HD + h * DH + lhi * 8;
        #pragma unroll
        for (int kk = 0; kk < 4; ++kk)
            qf[kk] = *reinterpret_cast<const bf16x8*>(qp + kk * 32);
    }

    f32x4 o[8] = {};
    float m_i = -1e30f;
    float l_i = 0.f;

    auto stage = [&](int t0, int buf) {
        char* Kl = fsm + buf * 32768;
        char* Vl = Kl + 16384;
        #pragma unroll
        for (int t = 0; t < 2; ++t) {
            int ch = t * 512 + tid;
            {
                int row = ch >> 4, ci = ch & 15;
                gload16(Kr + (size_t)(t0 + row) * GD + g * DH + ((ci ^ (row & 7)) << 3),
                        Kl + ch * 16);
            }
            {
                int d = ch >> 3, ci = ch & 7;
                gload16(VtG + (size_t)(g * DH + d) * S + t0 + ((ci ^ (d & 7)) << 3),
                        Vl + ch * 16);
            }
        }
    };

    const int nt = 2 * qt + 2;
    stage(0, 0);
    VMCNT(0);
    BARRIER();

    for (int it = 0; it < nt; ++it) {
        if (it + 1 < nt) stage((it + 1) * KVBLK, (it + 1) & 1);
        const char* Kl = fsm + (it & 1) * 32768;
        const char* Vl = Kl + 16384;
        if (it >= nt - 2)
            attn_tile<true>(it * KVBLK, q0w, l15, lhi, qf, Kl, Vl, Plw, o, m_i, l_i);
        else
            attn_tile<false>(it * KVBLK, q0w, l15, lhi, qf, Kl, Vl, Plw, o, m_i, l_i);
        VMCNT(0);
        BARRIER();
    }

    float lf[4];
    #pragma unroll
    for (int j = 0; j < 4; ++j) lf[j] = __shfl(l_i, lhi * 4 + j, 16);

    #pragma unroll
    for (int n = 0; n < 8; ++n) {
        int c = h * DH + n * 16 + l15;
        #pragma unroll
        for (int j = 0; j < 4; ++j) {
            int r = q0w + lhi * 4 + j;
            ctx[(size_t)r * HD + c] = (bf16)(o[n][j] / lf[j]);
        }
    }
}

// ---------------------------------------------------------------- launch
extern "C" void kernel_launch(void* const* d_in, const int* in_sizes, int n_in,
                              void* d_out, int out_size, void* d_ws, size_t ws_size,
                              hipStream_t stream)
{
    const float* x    = (const float*)d_in[0];
    const float* cosT = (const float*)d_in[2];
    const float* sinT = (const float*)d_in[3];
    const float* Wq   = (const float*)d_in[4];
    const float* Wk   = (const float*)d_in[5];
    const float* Wv   = (const float*)d_in[6];
    const float* Wo   = (const float*)d_in[7];
    float* out = (float*)d_out;

    const size_t MB = (size_t)1 << 20;
    char* ws = (char*)d_ws;
    bf16* xb  = (bf16*)ws;                         // 16MB
    bf16* ctx = (bf16*)(ws + 16 * MB);             // 16MB
    bf16* Qb  = (bf16*)d_out;                      // d_out scratch (dead until final GEMM)
    bf16* Kb  = Qb + (size_t)S * HD;
    bf16* Vb  = Kb + (size_t)S * GD;
    bf16* VtG = Vb + (size_t)S * GD;

    const bool fast = ws_size >= 112 * MB;
    const float qscale = 0.08838834764831845f * 1.4426950408889634f;

    hipFuncSetAttribute(reinterpret_cast<const void*>(&flash_fwd6),
                        hipFuncAttributeMaxDynamicSharedMemorySize, 81920);

    if (fast) {
        bf16* Wqkvt = (bf16*)(ws + 32 * MB);       // [6144][4096] bf16 = 48MB
        bf16* Wot   = (bf16*)(ws + 80 * MB);       // [4096][4096] bf16 = 32MB

        hipFuncSetAttribute(reinterpret_cast<const void*>(&gemm192q),
                            hipFuncAttributeMaxDynamicSharedMemorySize, 114688);
        hipFuncSetAttribute(reinterpret_cast<const void*>(&gemm3b),
                            hipFuncAttributeMaxDynamicSharedMemorySize, 147456);

        prep_fused<<<2048, 256, 0, stream>>>(x, xb, Wq, Wk, Wv, Wqkvt);

        gemm192q<<<256, 512, 114688, stream>>>(xb, Wqkvt, Qb, Kb, Vb, D);

        rope_vt_fused<<<20608, 256, 0, stream>>>(Qb, Kb, Vb, VtG, cosT, sinT, qscale);

        // flash + Wo transpose hidden in trailing 64 blocks
        flash_fwd6<<<FLASH_BLOCKS + 64, 512, 81920, stream>>>(
            Qb, Kb, VtG, ctx, Wo, Wot);

        gemm3b<<<256, 512, 147456, stream>>>(ctx, Wot, out, D, HD);
    } else {
        cast_f32_bf16<<<(S * D / 4 + 255) / 256, 256, 0, stream>>>(x, xb, S * D / 4);

        gemm_aBf16<true><<<dim3(HD / BN, S / BM, 1), 256, 0, stream>>>(
            xb, Wq, Wq, (void*)Qb, (void*)Qb, S, HD, D);
        gemm_aBf16<true><<<dim3(GD / BN, S / BM, 2), 256, 0, stream>>>(
            xb, Wk, Wv, (void*)Kb, (void*)Vb, S, GD, D);

        rope_inplace<<<(S * HD / 2 + 255) / 256, 256, 0, stream>>>(Qb, cosT, sinT, HD, S * HD / 2, qscale);
        rope_inplace<<<(S * GD / 2 + 255) / 256, 256, 0, stream>>>(Kb, cosT, sinT, GD, S * GD / 2, 1.0f);

        transpose_to_bf16<false><<<dim3(GD / 256, S / 64), 256, 0, stream>>>(Vb, VtG, S, GD);

        float* dummyWot = nullptr; (void)dummyWot;
        // fallback: transpose Wo via flash's trailing blocks too (需要 Wot); use ws tail
        bf16* WotF = (bf16*)(ws + 0);  // not used in fallback GEMM path
        (void)WotF;
        flash_fwd6<<<FLASH_BLOCKS, 512, 81920, stream>>>(Qb, Kb, VtG, ctx, Wo, (bf16*)ws);

        gemm_aBf16<false><<<dim3(D / BN, S / BM, 1), 256, 0, stream>>>(
            ctx, Wo, Wo, (void*)out, (void*)out, S, D, HD);
    }

    (void)in_sizes; (void)n_in; (void)out_size; (void)ws_size;
}

// Round 14
// 311.088 us; speedup vs baseline: 1.0865x; 1.0865x over previous
//
#include <hip/hip_runtime.h>
#include <hip/hip_bf16.h>
#include <cstdint>
#include <cstddef>

#define S 2048
#define D 4096
#define H 32
#define G 8
#define DH 128
#define HD (H*DH)   // 4096
#define GD (G*DH)   // 1024

typedef __bf16 bf16;
typedef __bf16 bf16x4 __attribute__((ext_vector_type(4)));
typedef __bf16 bf16x8 __attribute__((ext_vector_type(8)));
typedef float f32x4 __attribute__((ext_vector_type(4)));

__device__ __forceinline__ void gload16(const void* g, void* l) {
    __builtin_amdgcn_global_load_lds(
        (const __attribute__((address_space(1))) void*)g,
        (__attribute__((address_space(3))) void*)l, 16, 0, 0);
}

#define FENCE() asm volatile("" ::: "memory")
#define BARRIER() do { FENCE(); __builtin_amdgcn_s_barrier(); FENCE(); } while (0)
#define VMCNT(n)  asm volatile("s_waitcnt vmcnt(" #n ")" ::: "memory")
#define LGKM0()   do { asm volatile("s_waitcnt lgkmcnt(0)" ::: "memory"); \
                       __builtin_amdgcn_sched_barrier(0); } while (0)

// ---------------------------------------------------------------- fused prep:
// [0,512): cast x ; [512,1536): Wq^T ; [1536,1792): Wk^T ; [1792,2048): Wv^T
__global__ __launch_bounds__(256) void prep_fused(
    const float* __restrict__ x, bf16* __restrict__ xb,
    const float* __restrict__ Wq, const float* __restrict__ Wk,
    const float* __restrict__ Wv, bf16* __restrict__ Wqkvt)
{
    const int b = blockIdx.x, tid = threadIdx.x;
    if (b < 512) {
        int i = b * 4096 + tid;
        #pragma unroll
        for (int it = 0; it < 16; ++it, i += 256) {
            float4 v = reinterpret_cast<const float4*>(x)[i];
            bf16x4 o = { (bf16)v.x, (bf16)v.y, (bf16)v.z, (bf16)v.w };
            reinterpret_cast<bf16x4*>(xb)[i] = o;
        }
        return;
    }
    const float* in; bf16* out; int Cc, bx, by;
    if (b < 1536)      { int tb = b - 512;  in = Wq; out = Wqkvt;                       Cc = HD; bx = tb & 15; by = tb >> 4; }
    else if (b < 1792) { int tb = b - 1536; in = Wk; out = Wqkvt + (size_t)HD * D;      Cc = GD; bx = tb & 3;  by = tb >> 2; }
    else               { int tb = b - 1792; in = Wv; out = Wqkvt + (size_t)(HD+GD) * D; Cc = GD; bx = tb & 3;  by = tb >> 2; }
    const int r0 = by * 64 + (tid & 7) * 8;
    const int c0 = bx * 256 + (tid >> 3) * 8;
    bf16 m[8][8];
    #pragma unroll
    for (int j = 0; j < 8; ++j) {
        const float* p = in + (size_t)(r0 + j) * Cc + c0;
        float4 a = *reinterpret_cast<const float4*>(p);
        float4 bq = *reinterpret_cast<const float4*>(p + 4);
        m[j][0] = (bf16)a.x;  m[j][1] = (bf16)a.y;  m[j][2] = (bf16)a.z;  m[j][3] = (bf16)a.w;
        m[j][4] = (bf16)bq.x; m[j][5] = (bf16)bq.y; m[j][6] = (bf16)bq.z; m[j][7] = (bf16)bq.w;
    }
    #pragma unroll
    for (int i = 0; i < 8; ++i) {
        bf16x8 ov;
        #pragma unroll
        for (int j = 0; j < 8; ++j) ov[j] = m[j][i];
        *reinterpret_cast<bf16x8*>(out + (size_t)(c0 + i) * D + r0) = ov;
    }
}

// ---------------------------------------------------------------- fused rope + V^T
__global__ __launch_bounds__(256) void rope_vt_fused(
    bf16* __restrict__ Qb, bf16* __restrict__ Kb,
    const bf16* __restrict__ Vb, bf16* __restrict__ VtG,
    const float* __restrict__ cosT, const float* __restrict__ sinT, float qs)
{
    const int b = blockIdx.x, tid = threadIdx.x;
    if (b < 20480) {
        bf16* Y; int ncols, idx; float scale;
        if (b < 16384) { Y = Qb; ncols = HD; idx = b * 256 + tid;           scale = qs; }
        else           { Y = Kb; ncols = GD; idx = (b - 16384) * 256 + tid; scale = 1.0f; }
        int pairs = ncols >> 1;
        int s = idx / pairs;
        int p = idx - s * pairs;
        int head = p >> 6;
        int d = p & 63;
        size_t base = (size_t)s * ncols + head * DH;
        float c  = cosT[s * DH + d];
        float sn = sinT[s * DH + d];
        float a = (float)Y[base + d];
        float bb = (float)Y[base + d + 64];
        Y[base + d]      = (bf16)((a * c - bb * sn) * scale);
        Y[base + d + 64] = (bf16)((bb * c + a * sn) * scale);
        return;
    }
    const int tb = b - 20480;
    const int r0 = (tb >> 2) * 64 + (tid & 7) * 8;
    const int c0 = (tb & 3) * 256 + (tid >> 3) * 8;
    bf16 m[8][8];
    #pragma unroll
    for (int j = 0; j < 8; ++j) {
        bf16x8 v = *reinterpret_cast<const bf16x8*>(Vb + (size_t)(r0 + j) * GD + c0);
        #pragma unroll
        for (int i = 0; i < 8; ++i) m[j][i] = v[i];
    }
    #pragma unroll
    for (int i = 0; i < 8; ++i) {
        bf16x8 ov;
        #pragma unroll
        for (int j = 0; j < 8; ++j) ov[j] = m[j][i];
        *reinterpret_cast<bf16x8*>(VtG + (size_t)(c0 + i) * S + r0) = ov;
    }
}

// ---------------------------------------------------------------- standalone kernels (fallback path)
__global__ __launch_bounds__(256) void cast_f32_bf16(const float* __restrict__ in,
                                                     bf16* __restrict__ out, int n4)
{
    int i = blockIdx.x * 256 + threadIdx.x;
    if (i < n4) {
        float4 v = reinterpret_cast<const float4*>(in)[i];
        bf16x4 o = { (bf16)v.x, (bf16)v.y, (bf16)v.z, (bf16)v.w };
        reinterpret_cast<bf16x4*>(out)[i] = o;
    }
}

template<bool IN_F32>
__global__ __launch_bounds__(256) void transpose_to_bf16(
    const void* __restrict__ in, bf16* __restrict__ out, int R, int C)
{
    const int r0 = blockIdx.y * 64 + (threadIdx.x & 7) * 8;
    const int c0 = blockIdx.x * 256 + (threadIdx.x >> 3) * 8;
    bf16 m[8][8];
    #pragma unroll
    for (int j = 0; j < 8; ++j) {
        if constexpr (IN_F32) {
            const float* p = (const float*)in + (size_t)(r0 + j) * C + c0;
            float4 a = *reinterpret_cast<const float4*>(p);
            float4 b = *reinterpret_cast<const float4*>(p + 4);
            m[j][0] = (bf16)a.x; m[j][1] = (bf16)a.y; m[j][2] = (bf16)a.z; m[j][3] = (bf16)a.w;
            m[j][4] = (bf16)b.x; m[j][5] = (bf16)b.y; m[j][6] = (bf16)b.z; m[j][7] = (bf16)b.w;
        } else {
            const bf16* p = (const bf16*)in + (size_t)(r0 + j) * C + c0;
            bf16x8 v = *reinterpret_cast<const bf16x8*>(p);
            #pragma unroll
            for (int i = 0; i < 8; ++i) m[j][i] = v[i];
        }
    }
    #pragma unroll
    for (int i = 0; i < 8; ++i) {
        bf16x8 ov;
        #pragma unroll
        for (int j = 0; j < 8; ++j) ov[j] = m[j][i];
        *reinterpret_cast<bf16x8*>(out + (size_t)(c0 + i) * R + r0) = ov;
    }
}

__global__ __launch_bounds__(256) void rope_inplace(bf16* __restrict__ Y,
                                                    const float* __restrict__ cosT,
                                                    const float* __restrict__ sinT,
                                                    int ncols, int total, float scale)
{
    int idx = blockIdx.x * 256 + threadIdx.x;
    if (idx >= total) return;
    int pairs = ncols >> 1;
    int s = idx / pairs;
    int p = idx - s * pairs;
    int head = p >> 6;
    int d = p & 63;
    size_t base = (size_t)s * ncols + head * DH;
    float c  = cosT[s * DH + d];
    float sn = sinT[s * DH + d];
    float a = (float)Y[base + d];
    float b = (float)Y[base + d + 64];
    Y[base + d]      = (bf16)((a * c - b * sn) * scale);
    Y[base + d + 64] = (bf16)((b * c + a * sn) * scale);
}

// ================================================================ QKV GEMM: 256x192, 256 blocks, r4 schedule
__global__ __launch_bounds__(512) void gemm192q(
    const bf16* __restrict__ A, const bf16* __restrict__ Bt,
    bf16* __restrict__ Qout, bf16* __restrict__ Kout, bf16* __restrict__ Vout, int K)
{
    extern __shared__ char smem[];   // buf d @ d*57344: A 32KB | B @ +32768 (24KB)
    const int tid = threadIdx.x, lane = tid & 63, wave = tid >> 6;
    const int wr = wave >> 2, wc = wave & 3;
    const int l15 = lane & 15, lhi = lane >> 4;
    const int r8 = lane >> 3, c8 = lane & 7;
    const int csw = ((c8 ^ r8) << 3);

    const int x = blockIdx.x & 7, bi = blockIdx.x >> 3;
    const int brow = (x >> 2) * 4 + (bi & 3);       // [0,8)
    const int bcol = (x & 3) * 8 + (bi >> 2);       // [0,32)
    const int bm = brow * 256, bn = bcol * 192;
    const int NT = K >> 6;

    auto stA = [&](int buf, int h, int L, int t) {
        int row0 = L * 128 + h * 64 + wave * 8;
        gload16(A + (size_t)(bm + row0 + r8) * K + (t << 6) + csw,
                smem + buf * 57344 + row0 * 128);
    };
    auto stB = [&](int buf, int u, int t) {
        int row0 = u * 64 + wave * 8;
        gload16(Bt + (size_t)(bn + row0 + r8) * K + (t << 6) + csw,
                smem + buf * 57344 + 32768 + row0 * 128);
    };
    auto rdA = [&](const char* Cb, int mh, int ks, bf16x8* af) {
        #pragma unroll
        for (int m = 0; m < 4; ++m) {
            int row = wr * 128 + mh * 64 + m * 16 + l15;
            int ch = (ks * 4 + lhi) ^ (l15 & 7);
            af[m] = *reinterpret_cast<const bf16x8*>(Cb + row * 128 + ch * 16);
        }
    };
    auto rdB = [&](const char* Cb, int ks, bf16x8* bfv) {
        #pragma unroll
        for (int n = 0; n < 3; ++n) {
            int row = wc * 48 + n * 16 + l15;
            int ch = (ks * 4 + lhi) ^ (l15 & 7);
            bfv[n] = *reinterpret_cast<const bf16x8*>(Cb + 32768 + row * 128 + ch * 16);
        }
    };

    f32x4 acc[8][3] = {};
    auto mm = [&](int mh, const bf16x8* af, const bf16x8* bfv) {
        LGKM0();
        __builtin_amdgcn_s_setprio(1);
        #pragma unroll
        for (int m = 0; m < 4; ++m)
            #pragma unroll
            for (int n = 0; n < 3; ++n)
                acc[mh * 4 + m][n] = __builtin_amdgcn_mfma_f32_16x16x32_bf16(
                    af[m], bfv[n], acc[mh * 4 + m][n], 0, 0, 0);
        __builtin_amdgcn_s_setprio(0);
    };

    stB(0, 0, 0); stB(0, 1, 0); stB(0, 2, 0);
    stA(0, 0, 0, 0); stA(0, 0, 1, 0);
    stA(0, 1, 0, 0); stA(0, 1, 1, 0);
    VMCNT(2);
    BARRIER();

    for (int t = 0; t < NT; ++t) {
        const char* cur = smem + (t & 1) * 57344;
        const int nb = (t + 1) & 1;
        const int tn = (t + 1 < NT) ? t + 1 : t;
        bf16x8 af[4], bk0[3], bk1[3];

        // ph1: (mh0, ks0)
        rdA(cur, 0, 0, af); rdB(cur, 0, bk0);
        stB(nb, 0, tn); stB(nb, 1, tn);
        mm(0, af, bk0);
        BARRIER();

        // ph2: (mh0, ks1)
        rdA(cur, 0, 1, af); rdB(cur, 1, bk1);
        stB(nb, 2, tn); stA(nb, 0, 0, tn);
        mm(0, af, bk1);
        VMCNT(4);
        BARRIER();

        // ph3: (mh1, ks0)
        rdA(cur, 1, 0, af);
        stA(nb, 0, 1, tn); stA(nb, 1, 0, tn);
        mm(1, af, bk0);
        BARRIER();

        // ph4: (mh1, ks1)
        rdA(cur, 1, 1, af);
        stA(nb, 1, 1, tn);
        mm(1, af, bk1);
        VMCNT(2);
        BARRIER();
    }

    #pragma unroll
    for (int mm_i = 0; mm_i < 8; ++mm_i) {
        int r0 = bm + wr * 128 + (mm_i >> 2) * 64 + (mm_i & 3) * 16 + lhi * 4;
        #pragma unroll
        for (int n = 0; n < 3; ++n) {
            int c = bn + wc * 48 + n * 16 + l15;
            #pragma unroll
            for (int j = 0; j < 4; ++j) {
                bf16 v = (bf16)acc[mm_i][n][j];
                if (c < HD)            Qout[(size_t)(r0 + j) * HD + c] = v;
                else if (c < HD + GD)  Kout[(size_t)(r0 + j) * GD + (c - HD)] = v;
                else                   Vout[(size_t)(r0 + j) * GD + (c - HD - GD)] = v;
            }
        }
    }
}

// ================================================================ Wo GEMM: 256x128, 3-buf, 2D XCD regions
__global__ __launch_bounds__(512, 2) void gemm3b(
    const bf16* __restrict__ A, const bf16* __restrict__ Bt,
    float* __restrict__ C, int N, int K)
{
    extern __shared__ char smem[];   // buf b @ b*49152: A 32KB, B @ +32768 (16KB)
    const int tid = threadIdx.x, lane = tid & 63, wave = tid >> 6;
    const int wr = wave >> 1, wc = wave & 1;
    const int l15 = lane & 15, lhi = lane >> 4;
    const int r8 = lane >> 3, c8 = lane & 7;
    const int csw = ((c8 ^ r8) << 3);

    const int x = blockIdx.x & 7, i = blockIdx.x >> 3;
    const int brow = (x >> 2) * 4 + (i & 3);
    const int bcol = (x & 3) * 8 + (i >> 2);
    const int bm = brow * 256, bn = bcol * 128;
    const int NT = K >> 6;

    auto stageA = [&](int buf, int L, int t) {
        int row0 = L * 64 + wave * 8;
        gload16(A + (size_t)(bm + row0 + r8) * K + (t << 6) + csw,
                smem + buf * 49152 + row0 * 128);
    };
    auto stageB = [&](int buf, int L, int t) {
        int row0 = L * 64 + wave * 8;
        gload16(Bt + (size_t)(bn + row0 + r8) * K + (t << 6) + csw,
                smem + buf * 49152 + 32768 + row0 * 128);
    };
    auto rdA = [&](const char* Ab, int ks, bf16x8* af) {
        #pragma unroll
        for (int m = 0; m < 4; ++m) {
            int row = wr * 64 + m * 16 + l15;
            int ch = (ks * 4 + lhi) ^ (l15 & 7);
            af[m] = *reinterpret_cast<const bf16x8*>(Ab + row * 128 + ch * 16);
        }
    };
    auto rdB = [&](const char* Bb, int ks, bf16x8* bfv) {
        #pragma unroll
        for (int n = 0; n < 4; ++n) {
            int row = wc * 64 + n * 16 + l15;
            int ch = (ks * 4 + lhi) ^ (l15 & 7);
            bfv[n] = *reinterpret_cast<const bf16x8*>(Bb + row * 128 + ch * 16);
        }
    };

    f32x4 acc[4][4] = {};

    #pragma unroll
    for (int L = 0; L < 4; ++L) stageA(0, L, 0);
    stageB(0, 0, 0); stageB(0, 1, 0);
    #pragma unroll
    for (int L = 0; L < 4; ++L) stageA(1, L, (1 < NT) ? 1 : 0);
    stageB(1, 0, (1 < NT) ? 1 : 0); stageB(1, 1, (1 < NT) ? 1 : 0);
    VMCNT(6);
    BARRIER();

    for (int t = 0; t < NT; ++t) {
        const char* Ab = smem + (t % 3) * 49152;
        const char* Bb = Ab + 32768;
        const int b2 = (t + 2) % 3;
        const int st = (t + 2 < NT) ? t + 2 : NT - 1;
        bf16x8 af[4], bk[4];

        rdB(Bb, 0, bk); rdA(Ab, 0, af);
        stageA(b2, 0, st); stageA(b2, 1, st);
        LGKM0();
        __builtin_amdgcn_s_setprio(1);
        #pragma unroll
        for (int m = 0; m < 4; ++m)
            #pragma unroll
            for (int n = 0; n < 4; ++n)
                acc[m][n] = __builtin_amdgcn_mfma_f32_16x16x32_bf16(af[m], bk[n], acc[m][n], 0, 0, 0);
        __builtin_amdgcn_s_setprio(0);

        rdB(Bb, 1, bk); rdA(Ab, 1, af);
        stageA(b2, 2, st); stageA(b2, 3, st);
        stageB(b2, 0, st); stageB(b2, 1, st);
        LGKM0();
        __builtin_amdgcn_s_setprio(1);
        #pragma unroll
        for (int m = 0; m < 4; ++m)
            #pragma unroll
            for (int n = 0; n < 4; ++n)
                acc[m][n] = __builtin_amdgcn_mfma_f32_16x16x32_bf16(af[m], bk[n], acc[m][n], 0, 0, 0);
        __builtin_amdgcn_s_setprio(0);

        VMCNT(6);
        BARRIER();
    }

    #pragma unroll
    for (int m = 0; m < 4; ++m) {
        int r0 = bm + wr * 64 + m * 16 + lhi * 4;
        #pragma unroll
        for (int n = 0; n < 4; ++n) {
            int c = bn + wc * 64 + n * 16 + l15;
            #pragma unroll
            for (int j = 0; j < 4; ++j)
                C[(size_t)(r0 + j) * N + c] = acc[m][n][j];
        }
    }
}

// ---------------------------------------------------------------- fallback GEMM (round-1)
#define BM 128
#define BN 128
#define BK 32
#define LDSK 40

template<bool OUT_BF16>
__global__ __launch_bounds__(256) void gemm_aBf16(
    const bf16* __restrict__ A,
    const float* __restrict__ B0, const float* __restrict__ B1,
    void* __restrict__ C0, void* __restrict__ C1,
    int M, int N, int K)
{
    __shared__ alignas(16) bf16 Al[BM][LDSK];
    __shared__ alignas(16) bf16 Bt[BN][LDSK];

    const float* __restrict__ B = blockIdx.z ? B1 : B0;
    void* __restrict__ C = blockIdx.z ? C1 : C0;

    const int tid  = threadIdx.x;
    const int lane = tid & 63;
    const int wave = tid >> 6;
    const int wm = (wave >> 1) * 64;
    const int wn = (wave & 1) * 64;
    const int bm = blockIdx.y * BM;
    const int bn = blockIdx.x * BN;
    const int l15 = lane & 15;
    const int lhi = lane >> 4;

    f32x4 acc[4][4] = {};

    for (int k0 = 0; k0 < K; k0 += BK) {
        #pragma unroll
        for (int it = 0; it < 2; ++it) {
            int idx = it * 256 + tid;
            int row = idx >> 2;
            int ko  = idx & 3;
            bf16x8 v = *reinterpret_cast<const bf16x8*>(
                A + (size_t)(bm + row) * K + k0 + ko * 8);
            *reinterpret_cast<bf16x8*>(&Al[row][ko * 8]) = v;
        }
        {
            int n = tid & 127;
            int kbase = (tid >> 7) * 8;
            const float* bp = B + (size_t)k0 * N + bn + n;
            #pragma unroll
            for (int half = 0; half < 2; ++half) {
                bf16x8 v;
                #pragma unroll
                for (int j = 0; j < 8; ++j)
                    v[j] = (bf16)bp[(size_t)(half * 16 + kbase + j) * N];
                *reinterpret_cast<bf16x8*>(&Bt[n][half * 16 + kbase]) = v;
            }
        }
        __syncthreads();

        bf16x8 af[4], bfv[4];
        #pragma unroll
        for (int m = 0; m < 4; ++m)
            af[m] = *reinterpret_cast<const bf16x8*>(&Al[wm + m * 16 + l15][lhi * 8]);
        #pragma unroll
        for (int n = 0; n < 4; ++n)
            bfv[n] = *reinterpret_cast<const bf16x8*>(&Bt[wn + n * 16 + l15][lhi * 8]);
        #pragma unroll
        for (int m = 0; m < 4; ++m)
            #pragma unroll
            for (int n = 0; n < 4; ++n)
                acc[m][n] = __builtin_amdgcn_mfma_f32_16x16x32_bf16(
                    af[m], bfv[n], acc[m][n], 0, 0, 0);
        __syncthreads();
    }

    #pragma unroll
    for (int m = 0; m < 4; ++m) {
        int r0 = bm + wm + m * 16 + lhi * 4;
        #pragma unroll
        for (int n = 0; n < 4; ++n) {
            int c = bn + wn + n * 16 + l15;
            #pragma unroll
            for (int j = 0; j < 4; ++j) {
                if constexpr (OUT_BF16)
                    reinterpret_cast<bf16*>(C)[(size_t)(r0 + j) * N + c] = (bf16)acc[m][n][j];
                else
                    reinterpret_cast<float*>(C)[(size_t)(r0 + j) * N + c] = acc[m][n][j];
            }
        }
    }
}

// ---------------------------------------------------------------- flash attention v6 + Wo transpose FIRST
// Blocks [0,ntrans): Wo f32 -> Wot bf16 transpose (pure BW, retires in ~15-20us,
// releasing slots to the SHORTEST flash blocks). Blocks [ntrans, ntrans+512): flash,
// longest q-tiles first (they start at t=0 and set the critical path).
#define QBLK 128
#define KVBLK 64
#define NQT (S/QBLK)
#define FLASH_BLOCKS (NQT*H)

template<bool MASK>
__device__ __forceinline__ void attn_tile(
    int t0, int q0w, int l15, int lhi,
    const bf16x8* qf, const char* Kl, const char* Vl, char* Plw,
    f32x4* o, float& m_i, float& l_i)
{
    f32x4 sc[4] = {};
    __builtin_amdgcn_s_setprio(1);
    #pragma unroll
    for (int n = 0; n < 4; ++n) {
        int row = n * 16 + l15;
        #pragma unroll
        for (int kk = 0; kk < 4; ++kk) {
            bf16x8 kf = *reinterpret_cast<const bf16x8*>(
                Kl + row * 256 + ((((kk * 4 + lhi)) ^ (l15 & 7)) << 4));
            sc[n] = __builtin_amdgcn_mfma_f32_16x16x32_bf16(kf, qf[kk], sc[n], 0, 0, 0);
        }
    }
    __builtin_amdgcn_s_setprio(0);

    const int qr = q0w + l15;
    float vals[16];
    #pragma unroll
    for (int n = 0; n < 4; ++n)
        #pragma unroll
        for (int j = 0; j < 4; ++j) {
            float v = sc[n][j];
            if constexpr (MASK) {
                int t = t0 + n * 16 + lhi * 4 + j;
                if (t > qr) v = -1e30f;
            }
            vals[n * 4 + j] = v;
        }

    float m8[8], m4[4];
    #pragma unroll
    for (int k = 0; k < 8; ++k) m8[k] = fmaxf(vals[k], vals[k + 8]);
    #pragma unroll
    for (int k = 0; k < 4; ++k) m4[k] = fmaxf(m8[k], m8[k + 4]);
    float mx = fmaxf(fmaxf(m4[0], m4[1]), fmaxf(m4[2], m4[3]));
    mx = fmaxf(mx, __shfl_xor(mx, 16));
    mx = fmaxf(mx, __shfl_xor(mx, 32));

    const float mnew = (mx <= m_i + 8.0f) ? m_i : mx;
    const float cr = exp2f(m_i - mnew);

    float p[16];
    #pragma unroll
    for (int k = 0; k < 16; ++k) p[k] = exp2f(vals[k] - mnew);
    float s8[8], s4[4];
    #pragma unroll
    for (int k = 0; k < 8; ++k) s8[k] = p[k] + p[k + 8];
    #pragma unroll
    for (int k = 0; k < 4; ++k) s4[k] = s8[k] + s8[k + 4];
    float rsum = (s4[0] + s4[1]) + (s4[2] + s4[3]);
    rsum += __shfl_xor(rsum, 16);
    rsum += __shfl_xor(rsum, 32);
    l_i = l_i * cr + rsum;
    m_i = mnew;

    #pragma unroll
    for (int n = 0; n < 4; ++n) {
        bf16x4 w = { (bf16)p[n*4+0], (bf16)p[n*4+1], (bf16)p[n*4+2], (bf16)p[n*4+3] };
        int off = (l15 << 7) + (((n << 5) + (lhi << 3)) ^ ((l15 & 7) << 4));
        *reinterpret_cast<bf16x4*>(Plw + off) = w;
    }

    float corr[4];
    #pragma unroll
    for (int j = 0; j < 4; ++j) corr[j] = __shfl(cr, lhi * 4 + j, 16);
    if ((corr[0] != 1.f) | (corr[1] != 1.f) | (corr[2] != 1.f) | (corr[3] != 1.f)) {
        #pragma unroll
        for (int n = 0; n < 8; ++n)
            #pragma unroll
            for (int j = 0; j < 4; ++j)
                o[n][j] *= corr[j];
    }

    __builtin_amdgcn_s_setprio(1);
    #pragma unroll
    for (int kk = 0; kk < 2; ++kk) {
        bf16x8 pf = *reinterpret_cast<const bf16x8*>(
            Plw + (l15 << 7) + ((((kk * 4 + lhi)) ^ (l15 & 7)) << 4));
        #pragma unroll
        for (int n = 0; n < 8; ++n) {
            int d = n * 16 + l15;
            bf16x8 vf = *reinterpret_cast<const bf16x8*>(
                Vl + (d << 7) + ((((kk * 4 + lhi)) ^ (d & 7)) << 4));
            o[n] = __builtin_amdgcn_mfma_f32_16x16x32_bf16(pf, vf, o[n], 0, 0, 0);
        }
    }
    __builtin_amdgcn_s_setprio(0);
}

__global__ __launch_bounds__(512) void flash_fwd6(
    const bf16* __restrict__ Q, const bf16* __restrict__ Kr,
    const bf16* __restrict__ VtG, bf16* __restrict__ ctx,
    const float* __restrict__ WoIn, bf16* __restrict__ WotOut, int ntrans)
{
    extern __shared__ char fsm[];   // buf b: K @ b*32768, V @ +16384; P @ 65536 (8x2KB)

    const int tid  = threadIdx.x;
    const int bid = blockIdx.x;

    if (bid < ntrans) {
        // ---- Wo transpose first: retires early, backfilled by short flash blocks
        const int tb = bid;                              // 0..63
        const int r0 = tb * 64 + (tid & 7) * 8;          // rows of Wo (HD dim)
        #pragma unroll 1
        for (int pass = 0; pass < 8; ++pass) {
            const int c0 = pass * 512 + (tid >> 3) * 8;  // cols of Wo (D dim)
            bf16 m[8][8];
            #pragma unroll
            for (int j = 0; j < 8; ++j) {
                const float* p = WoIn + (size_t)(r0 + j) * D + c0;
                float4 a = *reinterpret_cast<const float4*>(p);
                float4 b = *reinterpret_cast<const float4*>(p + 4);
                m[j][0] = (bf16)a.x; m[j][1] = (bf16)a.y; m[j][2] = (bf16)a.z; m[j][3] = (bf16)a.w;
                m[j][4] = (bf16)b.x; m[j][5] = (bf16)b.y; m[j][6] = (bf16)b.z; m[j][7] = (bf16)b.w;
            }
            #pragma unroll
            for (int i = 0; i < 8; ++i) {
                bf16x8 ov;
                #pragma unroll
                for (int j = 0; j < 8; ++j) ov[j] = m[j][i];
                *reinterpret_cast<bf16x8*>(WotOut + (size_t)(c0 + i) * HD + r0) = ov;
            }
        }
        return;
    }

    const int fbid = bid - ntrans;
    const int lane = tid & 63;
    const int wave = tid >> 6;
    const int l15 = lane & 15;
    const int lhi = lane >> 4;
    const int qt = (NQT - 1) - (fbid >> 5);               // longest tiles first
    const int h  = ((fbid & 7) << 2) | ((fbid >> 3) & 3); // g == fbid%8 == XCD
    const int g  = h >> 2;
    const int q0 = qt * QBLK;
    const int q0w = q0 + wave * 16;
    char* Plw = fsm + 65536 + wave * 2048;

    bf16x8 qf[4];
    {
        const bf16* qp = Q + (size_t)(q0w + l15) * HD + h * DH + lhi * 8;
        #pragma unroll
        for (int kk = 0; kk < 4; ++kk)
            qf[kk] = *reinterpret_cast<const bf16x8*>(qp + kk * 32);
    }

    f32x4 o[8] = {};
    float m_i = -1e30f;
    float l_i = 0.f;

    auto stage = [&](int t0, int buf) {
        char* Kl = fsm + buf * 32768;
        char* Vl = Kl + 16384;
        #pragma unroll
        for (int t = 0; t < 2; ++t) {
            int ch = t * 512 + tid;
            {
                int row = ch >> 4, ci = ch & 15;
                gload16(Kr + (size_t)(t0 + row) * GD + g * DH + ((ci ^ (row & 7)) << 3),
                        Kl + ch * 16);
            }
            {
                int d = ch >> 3, ci = ch & 7;
                gload16(VtG + (size_t)(g * DH + d) * S + t0 + ((ci ^ (d & 7)) << 3),
                        Vl + ch * 16);
            }
        }
    };

    const int nt = 2 * qt + 2;
    stage(0, 0);
    VMCNT(0);
    BARRIER();

    for (int it = 0; it < nt; ++it) {
        if (it + 1 < nt) stage((it + 1) * KVBLK, (it + 1) & 1);
        const char* Kl = fsm + (it & 1) * 32768;
        const char* Vl = Kl + 16384;
        if (it >= nt - 2)
            attn_tile<true>(it * KVBLK, q0w, l15, lhi, qf, Kl, Vl, Plw, o, m_i, l_i);
        else
            attn_tile<false>(it * KVBLK, q0w, l15, lhi, qf, Kl, Vl, Plw, o, m_i, l_i);
        VMCNT(0);
        BARRIER();
    }

    float lf[4];
    #pragma unroll
    for (int j = 0; j < 4; ++j) lf[j] = __shfl(l_i, lhi * 4 + j, 16);

    #pragma unroll
    for (int n = 0; n < 8; ++n) {
        int c = h * DH + n * 16 + l15;
        #pragma unroll
        for (int j = 0; j < 4; ++j) {
            int r = q0w + lhi * 4 + j;
            ctx[(size_t)r * HD + c] = (bf16)(o[n][j] / lf[j]);
        }
    }
}

// ---------------------------------------------------------------- launch
extern "C" void kernel_launch(void* const* d_in, const int* in_sizes, int n_in,
                              void* d_out, int out_size, void* d_ws, size_t ws_size,
                              hipStream_t stream)
{
    const float* x    = (const float*)d_in[0];
    const float* cosT = (const float*)d_in[2];
    const float* sinT = (const float*)d_in[3];
    const float* Wq   = (const float*)d_in[4];
    const float* Wk   = (const float*)d_in[5];
    const float* Wv   = (const float*)d_in[6];
    const float* Wo   = (const float*)d_in[7];
    float* out = (float*)d_out;

    const size_t MB = (size_t)1 << 20;
    char* ws = (char*)d_ws;
    bf16* xb  = (bf16*)ws;                         // 16MB
    bf16* ctx = (bf16*)(ws + 16 * MB);             // 16MB
    bf16* Qb  = (bf16*)d_out;                      // d_out scratch (dead until final GEMM)
    bf16* Kb  = Qb + (size_t)S * HD;
    bf16* Vb  = Kb + (size_t)S * GD;
    bf16* VtG = Vb + (size_t)S * GD;

    const bool fast = ws_size >= 112 * MB;
    const float qscale = 0.08838834764831845f * 1.4426950408889634f;

    hipFuncSetAttribute(reinterpret_cast<const void*>(&flash_fwd6),
                        hipFuncAttributeMaxDynamicSharedMemorySize, 81920);

    if (fast) {
        bf16* Wqkvt = (bf16*)(ws + 32 * MB);       // [6144][4096] bf16 = 48MB
        bf16* Wot   = (bf16*)(ws + 80 * MB);       // [4096][4096] bf16 = 32MB

        hipFuncSetAttribute(reinterpret_cast<const void*>(&gemm192q),
                            hipFuncAttributeMaxDynamicSharedMemorySize, 114688);
        hipFuncSetAttribute(reinterpret_cast<const void*>(&gemm3b),
                            hipFuncAttributeMaxDynamicSharedMemorySize, 147456);

        prep_fused<<<2048, 256, 0, stream>>>(x, xb, Wq, Wk, Wv, Wqkvt);

        gemm192q<<<256, 512, 114688, stream>>>(xb, Wqkvt, Qb, Kb, Vb, D);

        rope_vt_fused<<<20608, 256, 0, stream>>>(Qb, Kb, Vb, VtG, cosT, sinT, qscale);

        // Wo transpose blocks FIRST, then flash (longest first)
        flash_fwd6<<<64 + FLASH_BLOCKS, 512, 81920, stream>>>(
            Qb, Kb, VtG, ctx, Wo, Wot, 64);

        gemm3b<<<256, 512, 147456, stream>>>(ctx, Wot, out, D, HD);
    } else {
        cast_f32_bf16<<<(S * D / 4 + 255) / 256, 256, 0, stream>>>(x, xb, S * D / 4);

        gemm_aBf16<true><<<dim3(HD / BN, S / BM, 1), 256, 0, stream>>>(
            xb, Wq, Wq, (void*)Qb, (void*)Qb, S, HD, D);
        gemm_aBf16<true><<<dim3(GD / BN, S / BM, 2), 256, 0, stream>>>(
            xb, Wk, Wv, (void*)Kb, (void*)Vb, S, GD, D);

        rope_inplace<<<(S * HD / 2 + 255) / 256, 256, 0, stream>>>(Qb, cosT, sinT, HD, S * HD / 2, qscale);
        rope_inplace<<<(S * GD / 2 + 255) / 256, 256, 0, stream>>>(Kb, cosT, sinT, GD, S * GD / 2, 1.0f);

        transpose_to_bf16<false><<<dim3(GD / 256, S / 64), 256, 0, stream>>>(Vb, VtG, S, GD);

        flash_fwd6<<<FLASH_BLOCKS, 512, 81920, stream>>>(
            Qb, Kb, VtG, ctx, Wo, (bf16*)ws, 0);

        gemm_aBf16<false><<<dim3(D / BN, S / BM, 1), 256, 0, stream>>>(
            ctx, Wo, Wo, (void*)out, (void*)out, S, D, HD);
    }

    (void)in_sizes; (void)n_in; (void)out_size; (void)ws_size;
}